// Round 18
// baseline (1279.527 us; speedup 1.0000x reference)
//
#include <hip/hip_runtime.h>

// MultilayerGRU — reference's indexing bug makes every (b,t) independent:
// 7 chained GEMMs over a 65536x512 activation matrix.
// Round 18: HYBRID OPERAND ROUTING. LDS pipe carries 48KB/block-step in R9
// (A+B staging writes + fragment reads) ~= 68µs/gates dispatch — the largest
// single pipe commitment. B (1.5MB weights, L2-resident) now reads fragments
// DIRECT from global with one-step register prefetch (4 loads in flight,
// ~400cyc cover; compiler auto-waits the registers). A keeps the proven
// gload_lds path (depth-1, 2 slots, verified 2-way-free swizzle). LDS traffic
// halves to 24KB/block-step. vmcnt: issue Astage(t+1) then Bf(t+1); vmcnt(4)
// at step end retires Astage(t+1), leaves Bf(t+1) in flight (FIFO-checked).

typedef __attribute__((ext_vector_type(4))) float f32x4;
typedef __attribute__((ext_vector_type(8))) __bf16 bf16x8;

#define NROWS 65536          // B*S
#define HID_OFF 33554432ull  // B*S*O floats, start of hidden_out in d_out

__device__ __forceinline__ void gload16(const void* g, void* l) {
  __builtin_amdgcn_global_load_lds((const __attribute__((address_space(1))) void*)g,
                                   (__attribute__((address_space(3))) void*)l,
                                   16, 0, 0);
}
__device__ __forceinline__ float sigmoidf_(float x) { return 1.f / (1.f + __expf(-x)); }
__device__ __forceinline__ float tanh_fast(float x) {
  const float e = __expf(2.f * x);
  return 1.f - 2.f / (e + 1.f);
}

// Stage one 128x32 bf16 A-tile (8KB) with 256 threads into linear LDS.
// LDS[row][slot] holds global chunk (slot ^ ((row>>1)&3)) -> swizzled read
// below is bank-conflict-free (2-way only, free per m136). Verified R9/R12.
__device__ __forceinline__ void stage32(const __bf16* __restrict__ src, int k0,
                                        __bf16* lds, int w, int lane) {
#pragma unroll
  for (int i = 0; i < 2; ++i) {
    const int s0 = (w * 2 + i) * 64;   // wave-uniform chunk base
    const int s = s0 + lane;           // chunk 0..511
    const int row = s >> 2;            // 0..127
    const int cc = ((s & 3) ^ (row >> 1)) & 3;   // source chunk within row
    gload16(src + (size_t)row * 512 + k0 + cc * 8, lds + s0 * 8);
  }
}

// Swizzled fragment read from a [128][32] tile: slot = (lane>>4) ^ ((row>>1)&3).
// After the staging involution, lane receives global k-chunk (lane>>4) —
// matching the direct B-frag mapping below (dot product k-slot consistent).
__device__ __forceinline__ bf16x8 frag32(const __bf16* t, int row, int lane) {
  const int c = (((lane >> 4) ^ (row >> 1)) & 3);
  return *(const bf16x8*)(t + row * 32 + c * 8);
}

// Stage a 128x128 bf16 tile of haux (512-col row-major) into 32KB LDS.
__device__ __forceinline__ void stage_ht(const __bf16* __restrict__ src,
                                         __bf16* Ht, int w, int lane) {
#pragma unroll
  for (int i = 0; i < 8; ++i) {
    const int s0 = i * 256 + w * 64;   // 16B chunks, 16 per row
    const int s = s0 + lane;
    const int row = s >> 4, cc = s & 15;
    gload16(src + (size_t)row * 512 + cc * 8, Ht + s0 * 8);
  }
  asm volatile("s_waitcnt vmcnt(0)");
  __builtin_amdgcn_sched_barrier(0);
  __builtin_amdgcn_s_barrier();
  __builtin_amdgcn_sched_barrier(0);
}

// EPI: 0 = gates (N=1536: z|r|gpart), 1 = update (N=512), 2 = out (N=512)
template<int EPI, bool L0>
__global__ __launch_bounds__(256, 3) void gemm18(
    const __bf16* __restrict__ A,     // M x 512 row-major
    const __bf16* __restrict__ Bt,    // N x 512 (pre-transposed weights)
    int tiles_n, int row_off,
    const float* __restrict__ bias,
    const float* __restrict__ cterm,  // L0 gates: 64 x 1024 fp32
    const float* __restrict__ h0f,    // L0: hidden_state base (B x 3*512)
    const __bf16* __restrict__ haux,  // L>=1: h row-major
    const __bf16* __restrict__ zf,    // fragment buffer (EPI0 write / EPI1 read)
    const __bf16* __restrict__ gf,    // fragment buffer (EPI0 write / EPI1 read)
    __bf16* __restrict__ o_rh,        // EPI0: r*h row-major
    __bf16* __restrict__ o_h,         // EPI1: h row-major
    float* __restrict__ o_f)          // EPI1: hidden_out slot; EPI2: out
{
  __shared__ alignas(16) __bf16 smem[16384];   // 32KB: A dbuf 16KB; epi haux 32KB
  __bf16* const A0 = smem;
  __bf16* const A1 = smem + 4096;

  const int tid = threadIdx.x, lane = tid & 63, w = tid >> 6;

  // T1: bijective XCD swizzle (m204)
  int bid = blockIdx.x;
  {
    const int nwg = gridDim.x;
    const int q = nwg >> 3, r = nwg & 7;
    const int x = bid & 7, rest = bid >> 3;
    bid = (x < r ? x * (q + 1) : r * (q + 1) + (x - r) * q) + rest;
  }
  const int tm = bid / tiles_n;
  const int tn = bid - tm * tiles_n;
  const size_t arow0 = (size_t)tm * 128;
  const int brow0 = tn * 128;
  const __bf16* const Ab = A + arow0 * 512;

  const int wr = (w >> 1) * 64;
  const int wc = (w & 1) * 64;

  // direct B fragment base: lane -> (row = brow0+wc+(lane&15), k-chunk lane>>4)
  const __bf16* const Bp = Bt + ((size_t)brow0 + wc + (lane & 15)) * 512 + (lane >> 4) * 8;

  f32x4 acc[4][4];
  const f32x4 zz = {0.f, 0.f, 0.f, 0.f};
#pragma unroll
  for (int i = 0; i < 4; ++i)
#pragma unroll
    for (int j = 0; j < 4; ++j) acc[i][j] = zz;

  bf16x8 bf0[4], bf1[4];   // two B fragment register sets (static indexing)

  auto ldB = [&](int t, bf16x8 (&bf)[4]) {
#pragma unroll
    for (int i = 0; i < 4; ++i)
      bf[i] = *(const bf16x8*)(Bp + (size_t)i * 16 * 512 + t * 32);
  };

  // one k-step: stage A(t+1) [2 gload_lds, issued FIRST], prefetch B(t+1)
  // frags to registers, read A(t) frags from LDS, MFMA with B(t) regs
  // (loaded last step). vmcnt(4) retires Astage(t+1), leaves Bf(t+1) in flight.
  auto stepf = [&](int t, const __bf16* cA, __bf16* nA,
                   bf16x8 (&bfN)[4], bf16x8 (&bfC)[4]) {
    if (t < 15) {
      stage32(Ab, (t + 1) * 32, nA, w, lane);
      ldB(t + 1, bfN);
    }
    bf16x8 af[4];
#pragma unroll
    for (int i = 0; i < 4; ++i)
      af[i] = frag32(cA, wr + i * 16 + (lane & 15), lane);
#pragma unroll
    for (int mi = 0; mi < 4; ++mi)
#pragma unroll
      for (int ni = 0; ni < 4; ++ni)
        acc[mi][ni] = __builtin_amdgcn_mfma_f32_16x16x32_bf16(af[mi], bfC[ni], acc[mi][ni], 0, 0, 0);
    if (t < 15) {
      asm volatile("s_waitcnt vmcnt(4)");
      __builtin_amdgcn_sched_barrier(0);
    }
    __builtin_amdgcn_s_barrier();
    __builtin_amdgcn_sched_barrier(0);
  };

  // prologue: stage A(0), load B(0) frags; vmcnt(4) -> Astage(0) landed
  // (issued before the 4 B loads), B(0) regs auto-waited before first MFMA.
  stage32(Ab, 0, A0, w, lane);
  ldB(0, bf0);
  asm volatile("s_waitcnt vmcnt(4)");
  __builtin_amdgcn_sched_barrier(0);
  __builtin_amdgcn_s_barrier();
  __builtin_amdgcn_sched_barrier(0);

#pragma unroll 1
  for (int t = 0; t < 16; t += 2) {
    stepf(t,     A0, A1, bf1, bf0);   // stage A(t+1)->A1, prefetch B(t+1)->bf1
    stepf(t + 1, A1, A0, bf0, bf1);   // stage A(t+2)->A0, prefetch B(t+2)->bf0
  }

  // ---------------- epilogues ----------------
  const int fcol = lane & 15;
  const int frow = (lane >> 4) * 4;
  const int bb0 = (row_off + (int)arow0) >> 10;  // batch idx, uniform per tile

  if (EPI == 0) {
    if (tn < 4) {
      // z quadrant -> fragment-order store
      const size_t foff = ((size_t)(tm * 4 + tn)) * 16384 + (size_t)tid * 64;
      __bf16* zw = (__bf16*)zf;
#pragma unroll
      for (int mi = 0; mi < 4; ++mi) {
        bf16x8 p0, p1;
#pragma unroll
        for (int ni = 0; ni < 4; ++ni)
#pragma unroll
          for (int j = 0; j < 4; ++j) {
            const int gcol = brow0 + wc + ni * 16 + fcol;
            float c = acc[mi][ni][j] + bias[gcol];
            if (L0) c += cterm[bb0 * 1024 + gcol];
            const float v = sigmoidf_(c);
            const int idx = ni * 4 + j;
            if (idx < 8) p0[idx] = (__bf16)v; else p1[idx - 8] = (__bf16)v;
          }
        *(bf16x8*)(zw + foff + mi * 16) = p0;
        *(bf16x8*)(zw + foff + mi * 16 + 8) = p1;
      }
    } else if (tn < 8) {
      // r quadrant -> r*h row-major (h LDS-tiled for L>=1)
      if (!L0) stage_ht(haux + arow0 * 512 + (tn - 4) * 128, smem, w, lane);
#pragma unroll
      for (int mi = 0; mi < 4; ++mi)
#pragma unroll
        for (int ni = 0; ni < 4; ++ni)
#pragma unroll
          for (int j = 0; j < 4; ++j) {
            const int rloc = (int)arow0 + wr + mi * 16 + frow + j;
            const int gcol = brow0 + wc + ni * 16 + fcol;
            const int nn = gcol - 512;
            float c = acc[mi][ni][j] + bias[gcol];
            if (L0) c += cterm[bb0 * 1024 + gcol];
            const float rv = sigmoidf_(c);
            const float h = L0 ? h0f[bb0 * 1536 + nn]
                               : (float)smem[(wr + mi * 16 + frow + j) * 128 + wc + ni * 16 + fcol];
            o_rh[(size_t)rloc * 512 + nn] = (__bf16)(rv * h);
          }
    } else {
      // g-partial quadrant -> fragment-order store (raw + bias)
      const size_t foff = ((size_t)(tm * 4 + (tn - 8))) * 16384 + (size_t)tid * 64;
      __bf16* gw = (__bf16*)gf;
#pragma unroll
      for (int mi = 0; mi < 4; ++mi) {
        bf16x8 p0, p1;
#pragma unroll
        for (int ni = 0; ni < 4; ++ni)
#pragma unroll
          for (int j = 0; j < 4; ++j) {
            const int gcol = brow0 + wc + ni * 16 + fcol;
            const float v = acc[mi][ni][j] + bias[gcol];
            const int idx = ni * 4 + j;
            if (idx < 8) p0[idx] = (__bf16)v; else p1[idx - 8] = (__bf16)v;
          }
        *(bf16x8*)(gw + foff + mi * 16) = p0;
        *(bf16x8*)(gw + foff + mi * 16 + 8) = p1;
      }
    }
  } else if (EPI == 1) {
    // prefetch z/g fragments first (overlaps with stage_ht latency)
    const size_t foff = ((size_t)(tm * 4 + tn)) * 16384 + (size_t)tid * 64;
    bf16x8 zr[4][2], gr[4][2];
#pragma unroll
    for (int mi = 0; mi < 4; ++mi) {
      zr[mi][0] = *(const bf16x8*)(zf + foff + mi * 16);
      zr[mi][1] = *(const bf16x8*)(zf + foff + mi * 16 + 8);
      gr[mi][0] = *(const bf16x8*)(gf + foff + mi * 16);
      gr[mi][1] = *(const bf16x8*)(gf + foff + mi * 16 + 8);
    }
    if (!L0) stage_ht(haux + arow0 * 512 + tn * 128, smem, w, lane);
    const bool has_last = (o_f != nullptr) && ((tm & 7) == 7);
#pragma unroll
    for (int mi = 0; mi < 4; ++mi) {
#pragma unroll
      for (int ni = 0; ni < 4; ++ni)
#pragma unroll
        for (int j = 0; j < 4; ++j) {
          const int rloc = (int)arow0 + wr + mi * 16 + frow + j;
          const int gcol = brow0 + wc + ni * 16 + fcol;
          const int idx = ni * 4 + j;
          const float zv = (float)(idx < 8 ? zr[mi][0][idx] : zr[mi][1][idx - 8]);
          const float gp = (float)(idx < 8 ? gr[mi][0][idx] : gr[mi][1][idx - 8]);
          const float gv = tanh_fast(gp + acc[mi][ni][j]);
          const float h = L0 ? h0f[bb0 * 1536 + gcol]
                             : (float)smem[(wr + mi * 16 + frow + j) * 128 + wc + ni * 16 + fcol];
          const float hv = zv * h + (1.f - zv) * gv;
          o_h[(size_t)rloc * 512 + gcol] = (__bf16)hv;
          if (has_last && ((rloc & 1023) == 1023))
            o_f[(size_t)bb0 * 1536 + gcol] = (float)(__bf16)hv;
        }
    }
  } else {
#pragma unroll
    for (int mi = 0; mi < 4; ++mi)
#pragma unroll
      for (int ni = 0; ni < 4; ++ni)
#pragma unroll
        for (int j = 0; j < 4; ++j) {
          const int rloc = (int)arow0 + wr + mi * 16 + frow + j;
          const int gcol = brow0 + wc + ni * 16 + fcol;
          o_f[(size_t)rloc * 512 + gcol] = acc[mi][ni][j] + bias[gcol];
        }
  }
}

// ---- prep kernels (unchanged, passing) ----

__global__ void prep_pack(const float* __restrict__ Wzx, const float* __restrict__ Wzh,
                          const float* __restrict__ Wrx, const float* __restrict__ Wrh,
                          const float* __restrict__ Wgx, const float* __restrict__ Wgh,
                          const float* __restrict__ Wout,
                          __bf16* __restrict__ W1t, __bf16* __restrict__ Wght,
                          __bf16* __restrict__ Woutt)
{
  const int slot = blockIdx.z;
  const float* srcA;
  const float* srcB = nullptr;
  __bf16* dst;
  if (slot < 9) {
    const int l = slot / 3, g = slot % 3;
    srcA = (g == 0 ? Wzx : g == 1 ? Wrx : Wgx) + (size_t)l * 512 * 512;
    if (l > 0 && g < 2) srcB = (g == 0 ? Wzh : Wrh) + (size_t)l * 512 * 512;
    dst = W1t + (size_t)l * 1536 * 512 + (size_t)g * 512 * 512;
  } else if (slot < 12) {
    const int l = slot - 9;
    srcA = Wgh + (size_t)l * 512 * 512;
    dst = Wght + (size_t)l * 512 * 512;
  } else {
    srcA = Wout;
    dst = Woutt;
  }
  __shared__ float tile[32][33];
  const int k0 = blockIdx.x * 32;
  const int n0 = blockIdx.y * 32;
  const int tx = threadIdx.x;
  const int ty = threadIdx.y;
  for (int i = ty; i < 32; i += 8) {
    float v = srcA[(size_t)(k0 + i) * 512 + n0 + tx];
    if (srcB) v += srcB[(size_t)(k0 + i) * 512 + n0 + tx];
    tile[i][tx] = v;
  }
  __syncthreads();
  for (int i = ty; i < 32; i += 8)
    dst[(size_t)(n0 + i) * 512 + k0 + tx] = (__bf16)tile[tx][i];
}

__global__ void cterm_kernel(const float* __restrict__ hidden,
                             const float* __restrict__ Wzh,
                             const float* __restrict__ Wrh,
                             float* __restrict__ Cterm)
{
  const int idx = blockIdx.x * blockDim.x + threadIdx.x;
  const int b = idx >> 10;
  const int n = idx & 1023;
  const float* W = (n < 512 ? Wzh : Wrh);
  const int nn = n & 511;
  const float* h0 = hidden + (size_t)b * 1536;
  float acc = 0.f;
  for (int k = 0; k < 512; ++k) acc += h0[k] * W[(size_t)k * 512 + nn];
  Cterm[idx] = acc;
}

__global__ void small_prep(const float* __restrict__ bzx, const float* __restrict__ brx,
                           const float* __restrict__ bgx, const float* __restrict__ hidden,
                           float* __restrict__ bias1, float* __restrict__ out_hidden)
{
  const int idx = blockIdx.x * blockDim.x + threadIdx.x;
  if (idx < 3 * 1536) {
    const int l = idx / 1536, j = idx % 1536;
    const float* src = (j < 512 ? bzx : j < 1024 ? brx : bgx);
    bias1[idx] = src[l * 512 + (j & 511)];
  }
  const int hidx = idx - 3 * 1536;
  if (hidx >= 0 && hidx < 64 * 512) {
    const int b = hidx >> 9, n = hidx & 511;
    out_hidden[(size_t)b * 1536 + n] = hidden[(size_t)b * 1536 + n];
  }
}

__global__ void convert_x(const float* __restrict__ src, __bf16* __restrict__ dst, long n)
{
  const long i = ((long)blockIdx.x * blockDim.x + threadIdx.x) * 8;
  if (i >= n) return;
  const f32x4 a = *(const f32x4*)(src + i);
  const f32x4 b = *(const f32x4*)(src + i + 4);
  bf16x8 o;
  o[0] = (__bf16)a[0]; o[1] = (__bf16)a[1]; o[2] = (__bf16)a[2]; o[3] = (__bf16)a[3];
  o[4] = (__bf16)b[0]; o[5] = (__bf16)b[1]; o[6] = (__bf16)b[2]; o[7] = (__bf16)b[3];
  *(bf16x8*)(dst + i) = o;
}

extern "C" void kernel_launch(void* const* d_in, const int* in_sizes, int n_in,
                              void* d_out, int out_size, void* d_ws, size_t ws_size,
                              hipStream_t stream) {
  const float* input  = (const float*)d_in[0];
  const float* hidden = (const float*)d_in[1];
  const float* Wzx = (const float*)d_in[2];
  const float* bzx = (const float*)d_in[3];
  const float* Wzh = (const float*)d_in[4];
  const float* Wrx = (const float*)d_in[5];
  const float* brx = (const float*)d_in[6];
  const float* Wrh = (const float*)d_in[7];
  const float* Wgx = (const float*)d_in[8];
  const float* bgx = (const float*)d_in[9];
  const float* Wgh = (const float*)d_in[10];
  const float* Wout = (const float*)d_in[11];
  const float* bout = (const float*)d_in[12];

  float* out = (float*)d_out;
  float* out_hidden = out + HID_OFF;

  char* ws = (char*)d_ws;
  size_t off = 0;
  auto carve = [&](size_t bytes) -> void* {
    off = (off + 255) & ~(size_t)255;
    void* p = ws + off;
    off += bytes;
    return p;
  };

  __bf16* W1t   = (__bf16*)carve(3ull * 1536 * 512 * 2);
  __bf16* Wght  = (__bf16*)carve(3ull * 512 * 512 * 2);
  __bf16* Woutt = (__bf16*)carve(512ull * 512 * 2);
  float*  bias1 = (float*) carve(3ull * 1536 * 4);
  float*  Cterm = (float*) carve(64ull * 1024 * 4);
  const size_t fixed_end = off;

  long chunk_rows = NROWS;
  int C = 1;
  while (C < 32) {
    const size_t need = ((fixed_end + 255) & ~(size_t)255) +
                        5ull * (size_t)chunk_rows * 512 * 2 + 5 * 256;
    if (need <= ws_size) break;
    C *= 2;
    chunk_rows /= 2;
  }
  __bf16* bufA  = (__bf16*)carve((size_t)chunk_rows * 512 * 2);
  __bf16* bufB  = (__bf16*)carve((size_t)chunk_rows * 512 * 2);
  __bf16* zfrag = (__bf16*)carve((size_t)chunk_rows * 512 * 2);
  __bf16* rhb   = (__bf16*)carve((size_t)chunk_rows * 512 * 2);
  __bf16* gfrag = (__bf16*)carve((size_t)chunk_rows * 512 * 2);

  small_prep<<<(3 * 1536 + 64 * 512 + 255) / 256, 256, 0, stream>>>(
      bzx, brx, bgx, hidden, bias1, out_hidden);
  dim3 tp_grid(16, 16, 13), tp_blk(32, 8);
  prep_pack<<<tp_grid, tp_blk, 0, stream>>>(Wzx, Wzh, Wrx, Wrh, Wgx, Wgh, Wout,
                                            W1t, Wght, Woutt);
  cterm_kernel<<<65536 / 256, 256, 0, stream>>>(hidden, Wzh, Wrh, Cterm);

  for (int c = 0; c < C; ++c) {
    const long row_off = (long)c * chunk_rows;
    const long nelem = chunk_rows * 512;
    const int mt = (int)(chunk_rows / 128);

    convert_x<<<(int)((nelem / 8 + 255) / 256), 256, 0, stream>>>(
        input + (size_t)row_off * 512, bufA, nelem);

    // layer 0
    gemm18<0, true><<<mt * 12, 256, 0, stream>>>(
        bufA, W1t, 12, (int)row_off, bias1, Cterm, hidden, nullptr,
        zfrag, gfrag, rhb, nullptr, nullptr);
    gemm18<1, true><<<mt * 4, 256, 0, stream>>>(
        rhb, Wght, 4, (int)row_off, nullptr, nullptr, hidden, nullptr,
        zfrag, gfrag, nullptr, bufB, out_hidden + 512);

    // layer 1 (x == h == bufB)
    gemm18<0, false><<<mt * 12, 256, 0, stream>>>(
        bufB, W1t + 1536 * 512, 12, (int)row_off, bias1 + 1536, nullptr, nullptr, bufB,
        zfrag, gfrag, rhb, nullptr, nullptr);
    gemm18<1, false><<<mt * 4, 256, 0, stream>>>(
        rhb, Wght + 512 * 512, 4, (int)row_off, nullptr, nullptr, nullptr, bufB,
        zfrag, gfrag, nullptr, bufA, out_hidden + 1024);

    // layer 2 (x == h == bufA)
    gemm18<0, false><<<mt * 12, 256, 0, stream>>>(
        bufA, W1t + 2 * 1536 * 512, 12, (int)row_off, bias1 + 3072, nullptr, nullptr, bufA,
        zfrag, gfrag, rhb, nullptr, nullptr);
    gemm18<1, false><<<mt * 4, 256, 0, stream>>>(
        rhb, Wght + 2 * 512 * 512, 4, (int)row_off, nullptr, nullptr, nullptr, bufA,
        zfrag, gfrag, nullptr, bufB, nullptr);

    // output projection
    gemm18<2, false><<<mt * 4, 256, 0, stream>>>(
        bufB, Woutt, 4, (int)row_off, bout, nullptr, nullptr, nullptr,
        nullptr, nullptr, nullptr, nullptr, out + (size_t)row_off * 512);
  }
}

// Round 19
// 864.130 us; speedup vs baseline: 1.4807x; 1.4807x over previous
//
#include <hip/hip_runtime.h>

// MultilayerGRU — FINAL (round-9 structure; best of 18 rounds, 862µs, 
// reproduced twice). Derivation: the reference's faithful indexing bug
// (states[0] never written; layer l>=1 reads the value layer l-1 just wrote
// THIS timestep) removes all temporal recurrence -> the whole op is 7 chained
// GEMMs over a 65536x512 activation matrix:
//   per layer: X@[Wz|Wr|Wg] (fused sigmoid / r*h / g-partial epilogue) then
//   RH@Wgh (fused tanh + state update + last-timestep extract); then H3@Wout.
// Layers 1,2 have x==h so Wzx+Wzh / Wrx+Wrh are pre-summed at pack time.
// GEMM: 128x128/BK=32, depth-2 triple-buffered global_load_lds staging with
// counted vmcnt(4), 2-way-free LDS XOR swizzle (verified: conflicts
// 3.8e7->1e6), fragment-order z/g relay between gates and update kernels,
// bijective XCD swizzle (FETCH 299->45MB). Ten structural alternatives
// (R4-R18: depth 0/1/2, reg-dbuf, 256^2, B-in-reg, LDS-free, hybrid routing,
// 8-24 waves/CU) all land gates in 165-408µs with this as the floor.

typedef __attribute__((ext_vector_type(4))) float f32x4;
typedef __attribute__((ext_vector_type(8))) __bf16 bf16x8;

#define NROWS 65536          // B*S
#define HID_OFF 33554432ull  // B*S*O floats, start of hidden_out in d_out

__device__ __forceinline__ void gload16(const void* g, void* l) {
  __builtin_amdgcn_global_load_lds((const __attribute__((address_space(1))) void*)g,
                                   (__attribute__((address_space(3))) void*)l,
                                   16, 0, 0);
}
__device__ __forceinline__ float sigmoidf_(float x) { return 1.f / (1.f + __expf(-x)); }
__device__ __forceinline__ float tanh_fast(float x) {
  const float e = __expf(2.f * x);
  return 1.f - 2.f / (e + 1.f);
}

// Stage one 128x32 bf16 tile (8KB) with 256 threads into linear LDS.
// LDS[row][slot] holds global chunk (slot ^ ((row>>1)&3)) so the swizzled
// read below is bank-conflict-free (each quarter-wave hits all 8 bank-quads
// exactly twice; 2-way is free per m136).
__device__ __forceinline__ void stage32(const __bf16* __restrict__ src, int k0,
                                        __bf16* lds, int w, int lane) {
#pragma unroll
  for (int i = 0; i < 2; ++i) {
    const int s0 = (w * 2 + i) * 64;   // wave-uniform chunk base
    const int s = s0 + lane;           // chunk 0..511
    const int row = s >> 2;            // 0..127
    const int cc = ((s & 3) ^ (row >> 1)) & 3;   // source chunk within row
    gload16(src + (size_t)row * 512 + k0 + cc * 8, lds + s0 * 8);
  }
}

// Swizzled fragment read from a [128][32] tile: slot = (lane>>4) ^ ((row>>1)&3).
__device__ __forceinline__ bf16x8 frag32(const __bf16* t, int row, int lane) {
  const int c = (((lane >> 4) ^ (row >> 1)) & 3);
  return *(const bf16x8*)(t + row * 32 + c * 8);
}

// Stage a 128x128 bf16 tile of haux (512-col row-major) into 32KB LDS.
__device__ __forceinline__ void stage_ht(const __bf16* __restrict__ src,
                                         __bf16* Ht, int w, int lane) {
#pragma unroll
  for (int i = 0; i < 8; ++i) {
    const int s0 = i * 256 + w * 64;   // 16B chunks, 16 per row
    const int s = s0 + lane;
    const int row = s >> 4, cc = s & 15;
    gload16(src + (size_t)row * 512 + cc * 8, Ht + s0 * 8);
  }
  asm volatile("s_waitcnt vmcnt(0)");
  __builtin_amdgcn_sched_barrier(0);
  __builtin_amdgcn_s_barrier();
  __builtin_amdgcn_sched_barrier(0);
}

// EPI: 0 = gates (N=1536: z|r|gpart), 1 = update (N=512), 2 = out (N=512)
template<int EPI, bool L0>
__global__ __launch_bounds__(256, 3) void gemm9(
    const __bf16* __restrict__ A,     // M x 512 row-major
    const __bf16* __restrict__ Bt,    // N x 512 (pre-transposed weights)
    int tiles_n, int row_off,
    const float* __restrict__ bias,
    const float* __restrict__ cterm,  // L0 gates: 64 x 1024 fp32
    const float* __restrict__ h0f,    // L0: hidden_state base (B x 3*512)
    const __bf16* __restrict__ haux,  // L>=1: h row-major
    const __bf16* __restrict__ zf,    // fragment buffer (EPI0 write / EPI1 read)
    const __bf16* __restrict__ gf,    // fragment buffer (EPI0 write / EPI1 read)
    __bf16* __restrict__ o_rh,        // EPI0: r*h row-major
    __bf16* __restrict__ o_h,         // EPI1: h row-major
    float* __restrict__ o_f)          // EPI1: hidden_out slot; EPI2: out
{
  __shared__ alignas(16) __bf16 smem[24576];   // 48KB: 3 x (A 8KB + B 8KB)
  __bf16* const A0 = smem;
  __bf16* const B0 = smem + 4096;
  __bf16* const A1 = smem + 8192;
  __bf16* const B1 = smem + 12288;
  __bf16* const A2 = smem + 16384;
  __bf16* const B2 = smem + 20480;

  const int tid = threadIdx.x, lane = tid & 63, w = tid >> 6;

  // T1: bijective XCD swizzle (m204)
  int bid = blockIdx.x;
  {
    const int nwg = gridDim.x;
    const int q = nwg >> 3, r = nwg & 7;
    const int x = bid & 7, rest = bid >> 3;
    bid = (x < r ? x * (q + 1) : r * (q + 1) + (x - r) * q) + rest;
  }
  const int tm = bid / tiles_n;
  const int tn = bid - tm * tiles_n;
  const size_t arow0 = (size_t)tm * 128;
  const int brow0 = tn * 128;
  const __bf16* const Ab = A + arow0 * 512;
  const __bf16* const Bb = Bt + (size_t)brow0 * 512;

  const int wr = (w >> 1) * 64;
  const int wc = (w & 1) * 64;

  f32x4 acc[4][4];
  const f32x4 zz = {0.f, 0.f, 0.f, 0.f};
#pragma unroll
  for (int i = 0; i < 4; ++i)
#pragma unroll
    for (int j = 0; j < 4; ++j) acc[i][j] = zz;

  // one k-step: stage tile t+2 (depth-2), compute tile t.
  // waits: vm=4 -> tile t+1 landed (t+2's 4 loads stay in flight);
  //        vm=0 -> drain; vm=-1 -> none (last step).
  auto stepf = [&](int t, const __bf16* cA, const __bf16* cB,
                   __bf16* nA, __bf16* nB, int vm) {
    if (nA) {
      stage32(Ab, (t + 2) * 32, nA, w, lane);
      stage32(Bb, (t + 2) * 32, nB, w, lane);
    }
    bf16x8 af[4], bb4[4];
#pragma unroll
    for (int i = 0; i < 4; ++i) {
      af[i]  = frag32(cA, wr + i * 16 + (lane & 15), lane);
      bb4[i] = frag32(cB, wc + i * 16 + (lane & 15), lane);
    }
#pragma unroll
    for (int mi = 0; mi < 4; ++mi)
#pragma unroll
      for (int ni = 0; ni < 4; ++ni)
        acc[mi][ni] = __builtin_amdgcn_mfma_f32_16x16x32_bf16(af[mi], bb4[ni], acc[mi][ni], 0, 0, 0);
    if (vm == 4) {
      asm volatile("s_waitcnt vmcnt(4)");
      __builtin_amdgcn_sched_barrier(0);
    } else if (vm == 0) {
      asm volatile("s_waitcnt vmcnt(0)");
      __builtin_amdgcn_sched_barrier(0);
    }
    __builtin_amdgcn_s_barrier();
    __builtin_amdgcn_sched_barrier(0);
  };

  // prologue: stage tiles 0 and 1 (8 loads/wave); vmcnt(4) -> tile 0 landed,
  // tile 1 (4 loads) still in flight.
  stage32(Ab, 0, A0, w, lane);
  stage32(Bb, 0, B0, w, lane);
  stage32(Ab, 32, A1, w, lane);
  stage32(Bb, 32, B1, w, lane);
  asm volatile("s_waitcnt vmcnt(4)");
  __builtin_amdgcn_sched_barrier(0);
  __builtin_amdgcn_s_barrier();
  __builtin_amdgcn_sched_barrier(0);

  // steps 0..11 (stage tiles 2..13)
#pragma unroll 1
  for (int it = 0; it < 4; ++it) {
    const int t = it * 3;
    stepf(t,     A0, B0, A2, B2, 4);
    stepf(t + 1, A1, B1, A0, B0, 4);
    stepf(t + 2, A2, B2, A1, B1, 4);
  }
  // tail: t=12 stages 14, t=13 stages 15, t=14 drains, t=15 computes last
  stepf(12, A0, B0, A2, B2, 4);
  stepf(13, A1, B1, A0, B0, 4);
  stepf(14, A2, B2, nullptr, nullptr, 0);
  stepf(15, A0, B0, nullptr, nullptr, -1);

  // ---------------- epilogues ----------------
  const int fcol = lane & 15;
  const int frow = (lane >> 4) * 4;
  const int bb0 = (row_off + (int)arow0) >> 10;  // batch idx, uniform per tile

  if (EPI == 0) {
    if (tn < 4) {
      // z quadrant -> fragment-order store
      const size_t foff = ((size_t)(tm * 4 + tn)) * 16384 + (size_t)tid * 64;
      __bf16* zw = (__bf16*)zf;
#pragma unroll
      for (int mi = 0; mi < 4; ++mi) {
        bf16x8 p0, p1;
#pragma unroll
        for (int ni = 0; ni < 4; ++ni)
#pragma unroll
          for (int j = 0; j < 4; ++j) {
            const int gcol = brow0 + wc + ni * 16 + fcol;
            float c = acc[mi][ni][j] + bias[gcol];
            if (L0) c += cterm[bb0 * 1024 + gcol];
            const float v = sigmoidf_(c);
            const int idx = ni * 4 + j;
            if (idx < 8) p0[idx] = (__bf16)v; else p1[idx - 8] = (__bf16)v;
          }
        *(bf16x8*)(zw + foff + mi * 16) = p0;
        *(bf16x8*)(zw + foff + mi * 16 + 8) = p1;
      }
    } else if (tn < 8) {
      // r quadrant -> r*h row-major (h LDS-tiled for L>=1)
      if (!L0) stage_ht(haux + arow0 * 512 + (tn - 4) * 128, smem, w, lane);
#pragma unroll
      for (int mi = 0; mi < 4; ++mi)
#pragma unroll
        for (int ni = 0; ni < 4; ++ni)
#pragma unroll
          for (int j = 0; j < 4; ++j) {
            const int rloc = (int)arow0 + wr + mi * 16 + frow + j;
            const int gcol = brow0 + wc + ni * 16 + fcol;
            const int nn = gcol - 512;
            float c = acc[mi][ni][j] + bias[gcol];
            if (L0) c += cterm[bb0 * 1024 + gcol];
            const float rv = sigmoidf_(c);
            const float h = L0 ? h0f[bb0 * 1536 + nn]
                               : (float)smem[(wr + mi * 16 + frow + j) * 128 + wc + ni * 16 + fcol];
            o_rh[(size_t)rloc * 512 + nn] = (__bf16)(rv * h);
          }
    } else {
      // g-partial quadrant -> fragment-order store (raw + bias)
      const size_t foff = ((size_t)(tm * 4 + (tn - 8))) * 16384 + (size_t)tid * 64;
      __bf16* gw = (__bf16*)gf;
#pragma unroll
      for (int mi = 0; mi < 4; ++mi) {
        bf16x8 p0, p1;
#pragma unroll
        for (int ni = 0; ni < 4; ++ni)
#pragma unroll
          for (int j = 0; j < 4; ++j) {
            const int gcol = brow0 + wc + ni * 16 + fcol;
            const float v = acc[mi][ni][j] + bias[gcol];
            const int idx = ni * 4 + j;
            if (idx < 8) p0[idx] = (__bf16)v; else p1[idx - 8] = (__bf16)v;
          }
        *(bf16x8*)(gw + foff + mi * 16) = p0;
        *(bf16x8*)(gw + foff + mi * 16 + 8) = p1;
      }
    }
  } else if (EPI == 1) {
    // prefetch z/g fragments first (overlaps with stage_ht latency)
    const size_t foff = ((size_t)(tm * 4 + tn)) * 16384 + (size_t)tid * 64;
    bf16x8 zr[4][2], gr[4][2];
#pragma unroll
    for (int mi = 0; mi < 4; ++mi) {
      zr[mi][0] = *(const bf16x8*)(zf + foff + mi * 16);
      zr[mi][1] = *(const bf16x8*)(zf + foff + mi * 16 + 8);
      gr[mi][0] = *(const bf16x8*)(gf + foff + mi * 16);
      gr[mi][1] = *(const bf16x8*)(gf + foff + mi * 16 + 8);
    }
    if (!L0) stage_ht(haux + arow0 * 512 + tn * 128, smem, w, lane);
    const bool has_last = (o_f != nullptr) && ((tm & 7) == 7);
#pragma unroll
    for (int mi = 0; mi < 4; ++mi) {
#pragma unroll
      for (int ni = 0; ni < 4; ++ni)
#pragma unroll
        for (int j = 0; j < 4; ++j) {
          const int rloc = (int)arow0 + wr + mi * 16 + frow + j;
          const int gcol = brow0 + wc + ni * 16 + fcol;
          const int idx = ni * 4 + j;
          const float zv = (float)(idx < 8 ? zr[mi][0][idx] : zr[mi][1][idx - 8]);
          const float gp = (float)(idx < 8 ? gr[mi][0][idx] : gr[mi][1][idx - 8]);
          const float gv = tanh_fast(gp + acc[mi][ni][j]);
          const float h = L0 ? h0f[bb0 * 1536 + gcol]
                             : (float)smem[(wr + mi * 16 + frow + j) * 128 + wc + ni * 16 + fcol];
          const float hv = zv * h + (1.f - zv) * gv;
          o_h[(size_t)rloc * 512 + gcol] = (__bf16)hv;
          if (has_last && ((rloc & 1023) == 1023))
            o_f[(size_t)bb0 * 1536 + gcol] = (float)(__bf16)hv;
        }
    }
  } else {
#pragma unroll
    for (int mi = 0; mi < 4; ++mi)
#pragma unroll
      for (int ni = 0; ni < 4; ++ni)
#pragma unroll
        for (int j = 0; j < 4; ++j) {
          const int rloc = (int)arow0 + wr + mi * 16 + frow + j;
          const int gcol = brow0 + wc + ni * 16 + fcol;
          o_f[(size_t)rloc * 512 + gcol] = acc[mi][ni][j] + bias[gcol];
        }
  }
}

// ---- prep kernels (unchanged, passing) ----

__global__ void prep_pack(const float* __restrict__ Wzx, const float* __restrict__ Wzh,
                          const float* __restrict__ Wrx, const float* __restrict__ Wrh,
                          const float* __restrict__ Wgx, const float* __restrict__ Wgh,
                          const float* __restrict__ Wout,
                          __bf16* __restrict__ W1t, __bf16* __restrict__ Wght,
                          __bf16* __restrict__ Woutt)
{
  const int slot = blockIdx.z;
  const float* srcA;
  const float* srcB = nullptr;
  __bf16* dst;
  if (slot < 9) {
    const int l = slot / 3, g = slot % 3;
    srcA = (g == 0 ? Wzx : g == 1 ? Wrx : Wgx) + (size_t)l * 512 * 512;
    if (l > 0 && g < 2) srcB = (g == 0 ? Wzh : Wrh) + (size_t)l * 512 * 512;
    dst = W1t + (size_t)l * 1536 * 512 + (size_t)g * 512 * 512;
  } else if (slot < 12) {
    const int l = slot - 9;
    srcA = Wgh + (size_t)l * 512 * 512;
    dst = Wght + (size_t)l * 512 * 512;
  } else {
    srcA = Wout;
    dst = Woutt;
  }
  __shared__ float tile[32][33];
  const int k0 = blockIdx.x * 32;
  const int n0 = blockIdx.y * 32;
  const int tx = threadIdx.x;
  const int ty = threadIdx.y;
  for (int i = ty; i < 32; i += 8) {
    float v = srcA[(size_t)(k0 + i) * 512 + n0 + tx];
    if (srcB) v += srcB[(size_t)(k0 + i) * 512 + n0 + tx];
    tile[i][tx] = v;
  }
  __syncthreads();
  for (int i = ty; i < 32; i += 8)
    dst[(size_t)(n0 + i) * 512 + k0 + tx] = (__bf16)tile[tx][i];
}

__global__ void cterm_kernel(const float* __restrict__ hidden,
                             const float* __restrict__ Wzh,
                             const float* __restrict__ Wrh,
                             float* __restrict__ Cterm)
{
  const int idx = blockIdx.x * blockDim.x + threadIdx.x;
  const int b = idx >> 10;
  const int n = idx & 1023;
  const float* W = (n < 512 ? Wzh : Wrh);
  const int nn = n & 511;
  const float* h0 = hidden + (size_t)b * 1536;
  float acc = 0.f;
  for (int k = 0; k < 512; ++k) acc += h0[k] * W[(size_t)k * 512 + nn];
  Cterm[idx] = acc;
}

__global__ void small_prep(const float* __restrict__ bzx, const float* __restrict__ brx,
                           const float* __restrict__ bgx, const float* __restrict__ hidden,
                           float* __restrict__ bias1, float* __restrict__ out_hidden)
{
  const int idx = blockIdx.x * blockDim.x + threadIdx.x;
  if (idx < 3 * 1536) {
    const int l = idx / 1536, j = idx % 1536;
    const float* src = (j < 512 ? bzx : j < 1024 ? brx : bgx);
    bias1[idx] = src[l * 512 + (j & 511)];
  }
  const int hidx = idx - 3 * 1536;
  if (hidx >= 0 && hidx < 64 * 512) {
    const int b = hidx >> 9, n = hidx & 511;
    out_hidden[(size_t)b * 1536 + n] = hidden[(size_t)b * 1536 + n];
  }
}

__global__ void convert_x(const float* __restrict__ src, __bf16* __restrict__ dst, long n)
{
  const long i = ((long)blockIdx.x * blockDim.x + threadIdx.x) * 8;
  if (i >= n) return;
  const f32x4 a = *(const f32x4*)(src + i);
  const f32x4 b = *(const f32x4*)(src + i + 4);
  bf16x8 o;
  o[0] = (__bf16)a[0]; o[1] = (__bf16)a[1]; o[2] = (__bf16)a[2]; o[3] = (__bf16)a[3];
  o[4] = (__bf16)b[0]; o[5] = (__bf16)b[1]; o[6] = (__bf16)b[2]; o[7] = (__bf16)b[3];
  *(bf16x8*)(dst + i) = o;
}

extern "C" void kernel_launch(void* const* d_in, const int* in_sizes, int n_in,
                              void* d_out, int out_size, void* d_ws, size_t ws_size,
                              hipStream_t stream) {
  const float* input  = (const float*)d_in[0];
  const float* hidden = (const float*)d_in[1];
  const float* Wzx = (const float*)d_in[2];
  const float* bzx = (const float*)d_in[3];
  const float* Wzh = (const float*)d_in[4];
  const float* Wrx = (const float*)d_in[5];
  const float* brx = (const float*)d_in[6];
  const float* Wrh = (const float*)d_in[7];
  const float* Wgx = (const float*)d_in[8];
  const float* bgx = (const float*)d_in[9];
  const float* Wgh = (const float*)d_in[10];
  const float* Wout = (const float*)d_in[11];
  const float* bout = (const float*)d_in[12];

  float* out = (float*)d_out;
  float* out_hidden = out + HID_OFF;

  char* ws = (char*)d_ws;
  size_t off = 0;
  auto carve = [&](size_t bytes) -> void* {
    off = (off + 255) & ~(size_t)255;
    void* p = ws + off;
    off += bytes;
    return p;
  };

  __bf16* W1t   = (__bf16*)carve(3ull * 1536 * 512 * 2);
  __bf16* Wght  = (__bf16*)carve(3ull * 512 * 512 * 2);
  __bf16* Woutt = (__bf16*)carve(512ull * 512 * 2);
  float*  bias1 = (float*) carve(3ull * 1536 * 4);
  float*  Cterm = (float*) carve(64ull * 1024 * 4);
  const size_t fixed_end = off;

  long chunk_rows = NROWS;
  int C = 1;
  while (C < 32) {
    const size_t need = ((fixed_end + 255) & ~(size_t)255) +
                        5ull * (size_t)chunk_rows * 512 * 2 + 5 * 256;
    if (need <= ws_size) break;
    C *= 2;
    chunk_rows /= 2;
  }
  __bf16* bufA  = (__bf16*)carve((size_t)chunk_rows * 512 * 2);
  __bf16* bufB  = (__bf16*)carve((size_t)chunk_rows * 512 * 2);
  __bf16* zfrag = (__bf16*)carve((size_t)chunk_rows * 512 * 2);
  __bf16* rhb   = (__bf16*)carve((size_t)chunk_rows * 512 * 2);
  __bf16* gfrag = (__bf16*)carve((size_t)chunk_rows * 512 * 2);

  small_prep<<<(3 * 1536 + 64 * 512 + 255) / 256, 256, 0, stream>>>(
      bzx, brx, bgx, hidden, bias1, out_hidden);
  dim3 tp_grid(16, 16, 13), tp_blk(32, 8);
  prep_pack<<<tp_grid, tp_blk, 0, stream>>>(Wzx, Wzh, Wrx, Wrh, Wgx, Wgh, Wout,
                                            W1t, Wght, Woutt);
  cterm_kernel<<<65536 / 256, 256, 0, stream>>>(hidden, Wzh, Wrh, Cterm);

  for (int c = 0; c < C; ++c) {
    const long row_off = (long)c * chunk_rows;
    const long nelem = chunk_rows * 512;
    const int mt = (int)(chunk_rows / 128);

    convert_x<<<(int)((nelem / 8 + 255) / 256), 256, 0, stream>>>(
        input + (size_t)row_off * 512, bufA, nelem);

    // layer 0
    gemm9<0, true><<<mt * 12, 256, 0, stream>>>(
        bufA, W1t, 12, (int)row_off, bias1, Cterm, hidden, nullptr,
        zfrag, gfrag, rhb, nullptr, nullptr);
    gemm9<1, true><<<mt * 4, 256, 0, stream>>>(
        rhb, Wght, 4, (int)row_off, nullptr, nullptr, hidden, nullptr,
        zfrag, gfrag, nullptr, bufB, out_hidden + 512);

    // layer 1 (x == h == bufB)
    gemm9<0, false><<<mt * 12, 256, 0, stream>>>(
        bufB, W1t + 1536 * 512, 12, (int)row_off, bias1 + 1536, nullptr, nullptr, bufB,
        zfrag, gfrag, rhb, nullptr, nullptr);
    gemm9<1, false><<<mt * 4, 256, 0, stream>>>(
        rhb, Wght + 512 * 512, 4, (int)row_off, nullptr, nullptr, nullptr, bufB,
        zfrag, gfrag, nullptr, bufA, out_hidden + 1024);

    // layer 2 (x == h == bufA)
    gemm9<0, false><<<mt * 12, 256, 0, stream>>>(
        bufA, W1t + 2 * 1536 * 512, 12, (int)row_off, bias1 + 3072, nullptr, nullptr, bufA,
        zfrag, gfrag, rhb, nullptr, nullptr);
    gemm9<1, false><<<mt * 4, 256, 0, stream>>>(
        rhb, Wght + 2 * 512 * 512, 4, (int)row_off, nullptr, nullptr, nullptr, bufA,
        zfrag, gfrag, nullptr, bufB, nullptr);

    // output projection
    gemm9<2, false><<<mt * 4, 256, 0, stream>>>(
        bufB, Woutt, 4, (int)row_off, bout, nullptr, nullptr, nullptr,
        nullptr, nullptr, nullptr, nullptr, out + (size_t)row_off * 512);
  }
}